// Round 14
// baseline (245.216 us; speedup 1.0000x reference)
//
#include <hip/hip_runtime.h>
#include <hip/hip_bf16.h>

typedef unsigned int u32;
typedef unsigned short u16;
typedef unsigned char u8;
typedef __attribute__((ext_vector_type(8))) short short8;
typedef __attribute__((ext_vector_type(4))) float f32x4;
typedef __attribute__((ext_vector_type(2))) float f32x2;

#define N_NODES 100000
#define N_EDGES 1600000
#define N_GRAPHS 1024
#define BUK_SHIFT 7         // 128 nodes per bucket
#define NBUK 782            // ceil(100000 / 128)
#define BUK_CAP 2560        // mean fill 2046, sd ~45 -> +11 sigma headroom
#define SCAT_EPT 16         // edges per thread in bucket_scatter
#define SCAT_TILE (256 * SCAT_EPT)
#define FP8_S 64.0f         // ts3 pre-scale into e4m3 normal range
#define FP8_INV_S (1.0f / 64.0f)

// ---- bf16 helpers (RNE) ----
__device__ __forceinline__ float bflo(u32 u) { return __uint_as_float(u << 16); }
__device__ __forceinline__ float bfhi(u32 u) { return __uint_as_float(u & 0xFFFF0000u); }
__device__ __forceinline__ u32 bf1(float a) {
    u32 ua = __float_as_uint(a);
    ua += 0x7FFF + ((ua >> 16) & 1);
    return ua >> 16;
}
__device__ __forceinline__ u32 bfpack(float a, float b) {
    u32 ua = __float_as_uint(a);
    u32 ub = __float_as_uint(b);
    ua += 0x7FFF + ((ua >> 16) & 1);
    ub += 0x7FFF + ((ub >> 16) & 1);
    return (ua >> 16) | (ub & 0xFFFF0000u);
}
__device__ __forceinline__ void unpack8(uint4 v, float* f) {
    f[0] = bflo(v.x); f[1] = bfhi(v.x); f[2] = bflo(v.y); f[3] = bfhi(v.y);
    f[4] = bflo(v.z); f[5] = bfhi(v.z); f[6] = bflo(v.w); f[7] = bfhi(v.w);
}
// ---- fp8 (e4m3) helpers: HW cvt ----
__device__ __forceinline__ void unpack16f8(uint4 v, float* f) {
    f32x2 p0 = __builtin_amdgcn_cvt_pk_f32_fp8((int)v.x, false);
    f32x2 p1 = __builtin_amdgcn_cvt_pk_f32_fp8((int)v.x, true);
    f32x2 p2 = __builtin_amdgcn_cvt_pk_f32_fp8((int)v.y, false);
    f32x2 p3 = __builtin_amdgcn_cvt_pk_f32_fp8((int)v.y, true);
    f32x2 p4 = __builtin_amdgcn_cvt_pk_f32_fp8((int)v.z, false);
    f32x2 p5 = __builtin_amdgcn_cvt_pk_f32_fp8((int)v.z, true);
    f32x2 p6 = __builtin_amdgcn_cvt_pk_f32_fp8((int)v.w, false);
    f32x2 p7 = __builtin_amdgcn_cvt_pk_f32_fp8((int)v.w, true);
    f[0] = p0.x; f[1] = p0.y; f[2] = p1.x; f[3] = p1.y;
    f[4] = p2.x; f[5] = p2.y; f[6] = p3.x; f[7] = p3.y;
    f[8] = p4.x; f[9] = p4.y; f[10] = p5.x; f[11] = p5.y;
    f[12] = p6.x; f[13] = p6.y; f[14] = p7.x; f[15] = p7.y;
}
__device__ __forceinline__ u8 fp8_1(float a) {
    int r = __builtin_amdgcn_cvt_pk_fp8_f32(a, a, 0, false);
    return (u8)(r & 0xFF);
}

// ---- setup kernel: W transposes->bf16, zero PS, init gapped bucket cursors ----
__global__ __launch_bounds__(256) void setup_kernel(const float* __restrict__ W1,
                                                    const float* __restrict__ W2,
                                                    const float* __restrict__ W3,
                                                    u16* __restrict__ W1t,
                                                    u16* __restrict__ W2t,
                                                    u16* __restrict__ W3t,
                                                    float* __restrict__ PS,
                                                    int* __restrict__ bcursor) {
    int i = blockIdx.x * 256 + threadIdx.x;
    if (i < 8192) {                 // W1: [128][64] -> W1t [64][128]
        int n = i / 128, k = i % 128;
        W1t[i] = (u16)bf1(W1[(size_t)k * 64 + n]);
    } else if (i < 16384) {         // W2: [64][128] -> W2t [128][64]
        int j = i - 8192;
        int n = j / 64, k = j % 64;
        W2t[j] = (u16)bf1(W2[(size_t)k * 128 + n]);
    } else if (i < 32768) {         // W3: [128][128] -> W3t [128][128]
        int j = i - 16384;
        int n = j / 128, k = j % 128;
        W3t[j] = (u16)bf1(W3[(size_t)k * 128 + n]);
    } else if (i < 40960) {         // zero PS
        int j = i - 32768;
        float4 z = make_float4(0.f, 0.f, 0.f, 0.f);
        float4* p = (float4*)(PS + (size_t)j * 16);
        p[0] = z; p[1] = z; p[2] = z; p[3] = z;
    } else if (i < 40960 + NBUK) {  // gapped bucket cursors
        int b = i - 40960;
        bcursor[b] = b * BUK_CAP;
    }
}

// ---------------- scatter edges into gapped bucket order (packed) ----------------
__global__ __launch_bounds__(256) void bucket_scatter_kernel(const int* __restrict__ src,
                                                             const int* __restrict__ dst,
                                                             int* __restrict__ bcursor,
                                                             int* __restrict__ sorted, int E) {
    __shared__ int lhist[NBUK];
    __shared__ int lbase[NBUK];
    for (int i = threadIdx.x; i < NBUK; i += 256) lhist[i] = 0;
    __syncthreads();
    int base_i = blockIdx.x * SCAT_TILE;
    int s[SCAT_EPT], d[SCAT_EPT], lp[SCAT_EPT];
#pragma unroll
    for (int k = 0; k < SCAT_EPT; ++k) {
        int i = base_i + k * 256 + threadIdx.x;
        if (i < E) {
            s[k] = src[i];
            d[k] = dst[i];
            lp[k] = atomicAdd(&lhist[d[k] >> BUK_SHIFT], 1);
        }
    }
    __syncthreads();
    for (int b = threadIdx.x; b < NBUK; b += 256) {
        int c = lhist[b];
        lbase[b] = c ? atomicAdd(&bcursor[b], c) : 0;
    }
    __syncthreads();
#pragma unroll
    for (int k = 0; k < SCAT_EPT; ++k) {
        int i = base_i + k * 256 + threadIdx.x;
        if (i < E) {
            int b = d[k] >> BUK_SHIFT;
            sorted[lbase[b] + lp[k]] = (s[k] << BUK_SHIFT) | (d[k] & 127);
        }
    }
}

// ---- fused: per-bucket count + dinv + rowse(start,end) + gapped CSR fill ----
__global__ __launch_bounds__(256) void bucket_build_kernel(const int* __restrict__ sorted,
                                                           const int* __restrict__ bcursor,
                                                           int2* __restrict__ rowse,
                                                           float* __restrict__ dinv,
                                                           int* __restrict__ esrc, int n) {
    __shared__ int ncnt[128];
    __shared__ int sc[128];
    __shared__ int lbase[128];
    __shared__ int lcur[128];
    int tid = threadIdx.x;
    int b = blockIdx.x;
    int start = b * BUK_CAP;
    int end = bcursor[b];            // final cursor = start + bucket count
    if (tid < 128) ncnt[tid] = 0;
    __syncthreads();
    for (int j = start + tid; j < end; j += 256)
        atomicAdd(&ncnt[sorted[j] & 127], 1);
    __syncthreads();
    if (tid < 128) sc[tid] = ncnt[tid];
    __syncthreads();
    for (int off = 1; off < 128; off <<= 1) {
        int v = 0;
        if (tid < 128 && tid >= off) v = sc[tid - off];
        __syncthreads();
        if (tid < 128) sc[tid] += v;
        __syncthreads();
    }
    if (tid < 128) {
        int excl = sc[tid] - ncnt[tid];
        int pos = start + excl;
        lbase[tid] = pos;
        lcur[tid] = 0;
        int node = (b << BUK_SHIFT) + tid;
        if (node < n) {
            rowse[node] = make_int2(pos, pos + ncnt[tid]);
            dinv[node] = rsqrtf((float)ncnt[tid] + 1.0f);
        }
    }
    __syncthreads();
    for (int j = start + tid; j < end; j += 256) {
        int p = sorted[j];
        int ln = p & 127;
        int off = atomicAdd(&lcur[ln], 1);
        esrc[lbase[ln] + off] = p >> BUK_SHIFT;
    }
}

// ---------------- MFMA GEMM: C[M][NOUT] = A[M][K] @ Wt^T ----------------
// EPI=0: bf16 C = A@W ; EPI=1: bf16 C = dinv*relu(A@W+b) ; EPI=2: fp8 C = fp8(S*(A@W))
template <int K, int NOUT, int EPI, int A_F32>
__global__ __launch_bounds__(256) void mfma_gemm_kernel(const void* __restrict__ Aptr,
                                                        const u16* __restrict__ Wt,
                                                        const float* __restrict__ bias,
                                                        const float* __restrict__ dinv,
                                                        void* __restrict__ C, int M) {
    constexpr int KP = K + 8;
    constexpr int NK = K / 32;
    constexpr int NCT = NOUT / 16;
    constexpr int SUBS = 2;
    __shared__ u16 wlds[NOUT * KP];
    int tid = threadIdx.x;
    constexpr int TOT = NOUT * K / 8;
    const uint4* wt4 = (const uint4*)Wt;
    for (int i = tid; i < TOT; i += 256) {
        int r = i / (K / 8), kc = i % (K / 8);
        *(uint4*)&wlds[r * KP + kc * 8] = wt4[i];
    }
    __syncthreads();

    int lane = tid & 63;
    int w = tid >> 6;
    int row0 = blockIdx.x * 128 + w * 32;

    short8 afr[SUBS][NK];
#pragma unroll
    for (int sub = 0; sub < SUBS; ++sub) {
        int arow = row0 + sub * 16 + (lane & 15);
        arow = min(arow, M - 1);
        if (A_F32) {
            const float* Af = (const float*)Aptr;
            float dv = dinv[arow];
#pragma unroll
            for (int ks = 0; ks < NK; ++ks) {
                int k0 = ks * 32 + (lane >> 4) * 8;
                const float4* p = (const float4*)(Af + (size_t)arow * K + k0);
                float4 uu = p[0], vv = p[1];
                uint4 q;
                q.x = bfpack(dv * uu.x, dv * uu.y);
                q.y = bfpack(dv * uu.z, dv * uu.w);
                q.z = bfpack(dv * vv.x, dv * vv.y);
                q.w = bfpack(dv * vv.z, dv * vv.w);
                afr[sub][ks] = *(short8*)&q;
            }
        } else {
            const u16* Ab = (const u16*)Aptr;
#pragma unroll
            for (int ks = 0; ks < NK; ++ks) {
                int k0 = ks * 32 + (lane >> 4) * 8;
                afr[sub][ks] = *(const short8*)(Ab + (size_t)arow * K + k0);
            }
        }
    }

    for (int ct = 0; ct < NCT; ++ct) {
        int bcol = ct * 16 + (lane & 15);
        short8 bfr[NK];
#pragma unroll
        for (int ks = 0; ks < NK; ++ks) {
            int k0 = ks * 32 + (lane >> 4) * 8;
            bfr[ks] = *(const short8*)&wlds[bcol * KP + k0];
        }
        float bc = 0.0f;
        if (EPI == 1) bc = bias[bcol];
#pragma unroll
        for (int sub = 0; sub < SUBS; ++sub) {
            f32x4 acc = {0.0f, 0.0f, 0.0f, 0.0f};
#pragma unroll
            for (int ks = 0; ks < NK; ++ks)
                acc = __builtin_amdgcn_mfma_f32_16x16x32_bf16(afr[sub][ks], bfr[ks], acc,
                                                              0, 0, 0);
            int rbase = row0 + sub * 16 + (lane >> 4) * 4;
            if (rbase < M) {
                if (EPI == 0) {
#pragma unroll
                    for (int j = 0; j < 4; ++j)
                        ((u16*)C)[(size_t)(rbase + j) * NOUT + bcol] = (u16)bf1(acc[j]);
                } else if (EPI == 1) {
                    float4 dv4 = *(const float4*)(dinv + rbase);
                    float dvv[4] = {dv4.x, dv4.y, dv4.z, dv4.w};
#pragma unroll
                    for (int j = 0; j < 4; ++j) {
                        float o = dvv[j] * fmaxf(acc[j] + bc, 0.0f);
                        ((u16*)C)[(size_t)(rbase + j) * NOUT + bcol] = (u16)bf1(o);
                    }
                } else {   // EPI == 2: fp8 out, pre-scaled by FP8_S
#pragma unroll
                    for (int j = 0; j < 4; ++j)
                        ((u8*)C)[(size_t)(rbase + j) * NOUT + bcol] = fp8_1(acc[j] * FP8_S);
                }
            }
        }
    }
}

// ---- edge-parallel wave aggregation (F=64 layers, bf16), 2x-unrolled gather ----
// EPI=1: out = dv * relu(dv*acc + bias)     (agg1 -> pre-scaled h1')
// EPI=2: out = dv * acc                     (pre-agg2 on pre-scaled h1')
template <int F, int OUT_BF, int EPI>
__global__ __launch_bounds__(256) void pull_agg_w_kernel(const uint4* __restrict__ TS,
                                                         const int2* __restrict__ rowse,
                                                         const int* __restrict__ esrc,
                                                         const float* __restrict__ dinv,
                                                         const float* __restrict__ bias,
                                                         void* __restrict__ OUT, int n) {
    constexpr int TPN = F / 8;
    constexpr int EPG = 64 / TPN;
    int wid = threadIdx.x >> 6;
    int lane = threadIdx.x & 63;
    int node = blockIdx.x * 4 + wid;
    if (node >= n) return;
    int t = lane % TPN;
    int g = lane / TPN;
    float acc[8] = {0, 0, 0, 0, 0, 0, 0, 0};
    float f[8];
    int2 se = rowse[node];
    int j = se.x + g;
    for (; j + EPG < se.y; j += 2 * EPG) {
        int s0 = esrc[j];
        int s1 = esrc[j + EPG];
        uint4 v0 = TS[(size_t)s0 * TPN + t];
        uint4 v1 = TS[(size_t)s1 * TPN + t];
        unpack8(v0, f);
#pragma unroll
        for (int k = 0; k < 8; ++k) acc[k] += f[k];
        unpack8(v1, f);
#pragma unroll
        for (int k = 0; k < 8; ++k) acc[k] += f[k];
    }
    if (j < se.y) {
        int s = esrc[j];
        unpack8(TS[(size_t)s * TPN + t], f);
#pragma unroll
        for (int k = 0; k < 8; ++k) acc[k] += f[k];
    }
#pragma unroll
    for (int k = 0; k < 8; ++k) {
#pragma unroll
        for (int m = TPN; m < 64; m <<= 1) acc[k] += __shfl_xor(acc[k], m, 64);
    }
    if (g == 0) {
        unpack8(TS[(size_t)node * TPN + t], f);
#pragma unroll
        for (int k = 0; k < 8; ++k) acc[k] += f[k];
        float dv = dinv[node];
        float o[8];
        if (EPI == 2) {
#pragma unroll
            for (int k = 0; k < 8; ++k) o[k] = dv * acc[k];
        } else {
            const float4* bias4 = (const float4*)bias;
            float4 b0 = bias4[t * 2], b1v = bias4[t * 2 + 1];
            float bb[8] = {b0.x, b0.y, b0.z, b0.w, b1v.x, b1v.y, b1v.z, b1v.w};
#pragma unroll
            for (int k = 0; k < 8; ++k) o[k] = fmaxf(dv * acc[k] + bb[k], 0.0f);
            if (EPI == 1) {
#pragma unroll
                for (int k = 0; k < 8; ++k) o[k] *= dv;
            }
        }
        if (OUT_BF) {
            uint4 pv;
            pv.x = bfpack(o[0], o[1]); pv.y = bfpack(o[2], o[3]);
            pv.z = bfpack(o[4], o[5]); pv.w = bfpack(o[6], o[7]);
            ((uint4*)OUT)[(size_t)node * TPN + t] = pv;
        } else {
            float4* O4 = (float4*)OUT;
            O4[(size_t)node * (F / 4) + t * 2] = make_float4(o[0], o[1], o[2], o[3]);
            O4[(size_t)node * (F / 4) + t * 2 + 1] = make_float4(o[4], o[5], o[6], o[7]);
        }
    }
}

// ---- fused layer-3 aggregation + mean-pool, fp8 TS3 gather (16B/lane) ----
// 4 waves/block, ONE node per wave, grid = n/4 EXACT. TPN=8 lanes x uint4
// (16 fp8 each) per row -> 8 lane-loads/edge (half of round-12), 8 edge
// groups x 2-unroll = 16 chains. LDS run-length reduce -> coalesced atomics.
__global__ __launch_bounds__(256) void pull_agg_pool_kernel(const uint4* __restrict__ TS,
                                                            const int2* __restrict__ rowse,
                                                            const int* __restrict__ esrc,
                                                            const float* __restrict__ dinv,
                                                            const float* __restrict__ bias,
                                                            const int* __restrict__ batch,
                                                            float* __restrict__ PS, int n) {
    constexpr int TPN = 8;    // F=128 fp8: 8 lanes x 16 feats (16 B per lane)
    constexpr int EPG = 8;
    __shared__ float hrow[4][128];
    __shared__ int ib[4];
    int wid = threadIdx.x >> 6;
    int lane = threadIdx.x & 63;
    int node = blockIdx.x * 4 + wid;   // always < n (grid exact)
    int t = lane % TPN;
    int g = lane / TPN;
    float acc[16];
#pragma unroll
    for (int k = 0; k < 16; ++k) acc[k] = 0.0f;
    float f[16];
    int2 se = rowse[node];
    int j = se.x + g;
    int end = se.y;
    for (; j + EPG < end; j += 2 * EPG) {
        int s0 = esrc[j];
        int s1 = esrc[j + EPG];
        uint4 v0 = TS[(size_t)s0 * TPN + t];
        uint4 v1 = TS[(size_t)s1 * TPN + t];
        unpack16f8(v0, f);
#pragma unroll
        for (int k = 0; k < 16; ++k) acc[k] += f[k];
        unpack16f8(v1, f);
#pragma unroll
        for (int k = 0; k < 16; ++k) acc[k] += f[k];
    }
    if (j < end) {
        unpack16f8(TS[(size_t)esrc[j] * TPN + t], f);
#pragma unroll
        for (int k = 0; k < 16; ++k) acc[k] += f[k];
    }
#pragma unroll
    for (int k = 0; k < 16; ++k) {
        acc[k] += __shfl_xor(acc[k], 8, 64);
        acc[k] += __shfl_xor(acc[k], 16, 64);
        acc[k] += __shfl_xor(acc[k], 32, 64);
    }
    if (g == 0) {
        unpack16f8(TS[(size_t)node * TPN + t], f);
        float dvs = dinv[node] * FP8_INV_S;   // undo fp8 pre-scale
        const float4* bias4 = (const float4*)bias;
        float4 b0 = bias4[t * 4], b1v = bias4[t * 4 + 1];
        float4 b2v = bias4[t * 4 + 2], b3v = bias4[t * 4 + 3];
        float bb[16] = {b0.x, b0.y, b0.z, b0.w, b1v.x, b1v.y, b1v.z, b1v.w,
                        b2v.x, b2v.y, b2v.z, b2v.w, b3v.x, b3v.y, b3v.z, b3v.w};
#pragma unroll
        for (int k = 0; k < 16; ++k)
            hrow[wid][t * 16 + k] = fmaxf(dvs * (acc[k] + f[k]) + bb[k], 0.0f);
        if (lane == 0) ib[wid] = batch[node];
    }
    __syncthreads();
    // run-length reduce 4 node rows by graph id (batch sorted)
    int tf = threadIdx.x;
    if (tf < 128) {
        float run = hrow[0][tf];
        int cg = ib[0];
        for (int w = 1; w < 4; ++w) {
            int gg = ib[w];
            if (gg != cg) {
                atomicAdd(&PS[(size_t)cg * 128 + tf], run);
                run = hrow[w][tf];
                cg = gg;
            } else {
                run += hrow[w][tf];
            }
        }
        atomicAdd(&PS[(size_t)cg * 128 + tf], run);
    }
}

// ---------------- FC from pooled sums: out = (PS[g]/cnt) @ Wfc + bfc ----------------
__global__ __launch_bounds__(128) void fc_kernel(const float* __restrict__ PS,
                                                 const int* __restrict__ batch,
                                                 const float* __restrict__ Wfc,
                                                 const float* __restrict__ bfc,
                                                 float* __restrict__ OUT, int n) {
    int g = blockIdx.x;
    __shared__ int se[2];
    __shared__ float pooled[128];
    if (threadIdx.x < 2) {
        int target = g + threadIdx.x;
        int lo = 0, hi = n;
        while (lo < hi) {
            int mid = (lo + hi) >> 1;
            if (batch[mid] < target) lo = mid + 1; else hi = mid;
        }
        se[threadIdx.x] = lo;
    }
    __syncthreads();
    float cntf = (float)max(se[1] - se[0], 1);
    pooled[threadIdx.x] = PS[(size_t)g * 128 + threadIdx.x] / cntf;
    __syncthreads();
    if (threadIdx.x < 10) {
        float o = bfc[threadIdx.x];
        for (int k = 0; k < 128; ++k) o += pooled[k] * Wfc[k * 10 + threadIdx.x];
        OUT[g * 10 + threadIdx.x] = o;
    }
}

extern "C" void kernel_launch(void* const* d_in, const int* in_sizes, int n_in,
                              void* d_out, int out_size, void* d_ws, size_t ws_size,
                              hipStream_t stream) {
    const int N = N_NODES, E = N_EDGES, G = N_GRAPHS;
    const float* x = (const float*)d_in[0];
    const int* ei = (const int*)d_in[1];
    const int* batch = (const int*)d_in[2];
    const float* W1 = (const float*)d_in[3];
    const float* b1 = (const float*)d_in[4];
    const float* W2 = (const float*)d_in[5];
    const float* b2 = (const float*)d_in[6];
    const float* W3 = (const float*)d_in[7];
    const float* b3 = (const float*)d_in[8];
    const float* Wfc = (const float*)d_in[9];
    const float* bfc = (const float*)d_in[10];
    const int* src = ei;
    const int* dst = ei + E;

    char* ws = (char*)d_ws;
    size_t off = 0;
    auto alloc = [&](size_t bytes) {
        void* p = ws + off;
        off = (off + bytes + 255) & ~(size_t)255;
        return p;
    };
    float* dinv = (float*)alloc((size_t)N * 4);
    int2* rowse = (int2*)alloc((size_t)N * 8);
    int* bcursor = (int*)alloc((size_t)NBUK * 4);
    int* esrc = (int*)alloc((size_t)NBUK * BUK_CAP * 4);   // gapped, ~8 MB
    u16* W1t = (u16*)alloc((size_t)64 * 128 * 2);
    u16* W2t = (u16*)alloc((size_t)128 * 64 * 2);
    u16* W3t = (u16*)alloc((size_t)128 * 128 * 2);
    u16* TS1 = (u16*)alloc((size_t)N * 64 * 2);      // bf16 [N][64]
    u16* H1S = (u16*)alloc((size_t)N * 64 * 2);      // bf16 [N][64], pre-scaled
    u16* G2 = (u16*)alloc((size_t)N * 64 * 2);       // bf16 [N][64]
    u16* H2S = (u16*)alloc((size_t)N * 128 * 2);     // bf16 [N][128], pre-scaled
    u8* TS3 = (u8*)alloc((size_t)N * 128);           // fp8 [N][128], scaled by FP8_S
    float* PS = (float*)alloc((size_t)G * 128 * 4);  // pooled sums
    int* sorted = (int*)TS3;  // gapped packed edges (8 MB) alias TS3 (12.8 MB)

    // ---- setup: W conversion + PS zero + cursor init (one kernel, no memsets) ----
    setup_kernel<<<164, 256, 0, stream>>>(W1, W2, W3, W1t, W2t, W3t, PS, bcursor);
    // ---- graph preprocessing: gapped bucket sort + CSR build ----
    const int NTILES = (E + SCAT_TILE - 1) / SCAT_TILE;
    bucket_scatter_kernel<<<NTILES, 256, 0, stream>>>(src, dst, bcursor, sorted, E);
    bucket_build_kernel<<<NBUK, 256, 0, stream>>>(sorted, bcursor, rowse, dinv, esrc, N);

    const int GEMM_GRID = (N + 127) / 128;   // 782
    const int AGG_GRID = N / 4;              // 25000 (N%4==0)
    // ---- layer 1: 128 -> 64 ----
    mfma_gemm_kernel<128, 64, 0, 1><<<GEMM_GRID, 256, 0, stream>>>(x, W1t, nullptr, dinv,
                                                                   TS1, N);
    pull_agg_w_kernel<64, 1, 1><<<AGG_GRID, 256, 0, stream>>>((const uint4*)TS1, rowse,
                                                              esrc, dinv, b1, H1S, N);
    // ---- layer 2: 64 -> 128 ----
    pull_agg_w_kernel<64, 1, 2><<<AGG_GRID, 256, 0, stream>>>((const uint4*)H1S, rowse,
                                                              esrc, dinv, nullptr, G2, N);
    mfma_gemm_kernel<64, 128, 1, 0><<<GEMM_GRID, 256, 0, stream>>>(G2, W2t, b2, dinv,
                                                                   H2S, N);
    // ---- layer 3: 128 -> 128, fp8 ts3; aggregation fused with mean-pool ----
    mfma_gemm_kernel<128, 128, 2, 0><<<GEMM_GRID, 256, 0, stream>>>(H2S, W3t, nullptr, dinv,
                                                                    TS3, N);
    pull_agg_pool_kernel<<<AGG_GRID, 256, 0, stream>>>((const uint4*)TS3, rowse, esrc,
                                                       dinv, b3, batch, PS, N);
    // ---- FC from pooled sums ----
    fc_kernel<<<G, 128, 0, stream>>>(PS, batch, Wfc, bfc, (float*)d_out, N);
}

// Round 15
// 233.392 us; speedup vs baseline: 1.0507x; 1.0507x over previous
//
#include <hip/hip_runtime.h>
#include <hip/hip_bf16.h>

typedef unsigned int u32;
typedef unsigned short u16;
typedef unsigned char u8;
typedef __attribute__((ext_vector_type(8))) short short8;
typedef __attribute__((ext_vector_type(4))) float f32x4;
typedef __attribute__((ext_vector_type(2))) float f32x2;

#define N_NODES 100000
#define N_EDGES 1600000
#define N_GRAPHS 1024
#define BUK_SHIFT 7         // 128 nodes per bucket
#define NBUK 782            // ceil(100000 / 128)
#define BUK_CAP 2560        // mean fill 2046, sd ~45 -> +11 sigma headroom
#define SCAT_EPT 16         // edges per thread in bucket_scatter
#define SCAT_TILE (256 * SCAT_EPT)
#define FP8_S 64.0f         // ts pre-scale into e4m3 normal range
#define FP8_INV_S (1.0f / 64.0f)

// ---- bf16 helpers (RNE) ----
__device__ __forceinline__ float bflo(u32 u) { return __uint_as_float(u << 16); }
__device__ __forceinline__ float bfhi(u32 u) { return __uint_as_float(u & 0xFFFF0000u); }
__device__ __forceinline__ u32 bf1(float a) {
    u32 ua = __float_as_uint(a);
    ua += 0x7FFF + ((ua >> 16) & 1);
    return ua >> 16;
}
__device__ __forceinline__ u32 bfpack(float a, float b) {
    u32 ua = __float_as_uint(a);
    u32 ub = __float_as_uint(b);
    ua += 0x7FFF + ((ua >> 16) & 1);
    ub += 0x7FFF + ((ub >> 16) & 1);
    return (ua >> 16) | (ub & 0xFFFF0000u);
}
__device__ __forceinline__ void unpack8(uint4 v, float* f) {
    f[0] = bflo(v.x); f[1] = bfhi(v.x); f[2] = bflo(v.y); f[3] = bfhi(v.y);
    f[4] = bflo(v.z); f[5] = bfhi(v.z); f[6] = bflo(v.w); f[7] = bfhi(v.w);
}
// ---- fp8 (e4m3) helpers: HW cvt, 8 values per uint2 ----
__device__ __forceinline__ void unpack8f8(uint2 v, float* f) {
    f32x2 p0 = __builtin_amdgcn_cvt_pk_f32_fp8((int)v.x, false);
    f32x2 p1 = __builtin_amdgcn_cvt_pk_f32_fp8((int)v.x, true);
    f32x2 p2 = __builtin_amdgcn_cvt_pk_f32_fp8((int)v.y, false);
    f32x2 p3 = __builtin_amdgcn_cvt_pk_f32_fp8((int)v.y, true);
    f[0] = p0.x; f[1] = p0.y; f[2] = p1.x; f[3] = p1.y;
    f[4] = p2.x; f[5] = p2.y; f[6] = p3.x; f[7] = p3.y;
}
__device__ __forceinline__ u8 fp8_1(float a) {
    int r = __builtin_amdgcn_cvt_pk_fp8_f32(a, a, 0, false);
    return (u8)(r & 0xFF);
}

// ---- setup kernel: W transposes->bf16, zero PS, init gapped bucket cursors ----
__global__ __launch_bounds__(256) void setup_kernel(const float* __restrict__ W1,
                                                    const float* __restrict__ W2,
                                                    const float* __restrict__ W3,
                                                    u16* __restrict__ W1t,
                                                    u16* __restrict__ W2t,
                                                    u16* __restrict__ W3t,
                                                    float* __restrict__ PS,
                                                    int* __restrict__ bcursor) {
    int i = blockIdx.x * 256 + threadIdx.x;
    if (i < 8192) {                 // W1: [128][64] -> W1t [64][128]
        int n = i / 128, k = i % 128;
        W1t[i] = (u16)bf1(W1[(size_t)k * 64 + n]);
    } else if (i < 16384) {         // W2: [64][128] -> W2t [128][64]
        int j = i - 8192;
        int n = j / 64, k = j % 64;
        W2t[j] = (u16)bf1(W2[(size_t)k * 128 + n]);
    } else if (i < 32768) {         // W3: [128][128] -> W3t [128][128]
        int j = i - 16384;
        int n = j / 128, k = j % 128;
        W3t[j] = (u16)bf1(W3[(size_t)k * 128 + n]);
    } else if (i < 40960) {         // zero PS
        int j = i - 32768;
        float4 z = make_float4(0.f, 0.f, 0.f, 0.f);
        float4* p = (float4*)(PS + (size_t)j * 16);
        p[0] = z; p[1] = z; p[2] = z; p[3] = z;
    } else if (i < 40960 + NBUK) {  // gapped bucket cursors
        int b = i - 40960;
        bcursor[b] = b * BUK_CAP;
    }
}

// ---------------- scatter edges into gapped bucket order (packed) ----------------
__global__ __launch_bounds__(256) void bucket_scatter_kernel(const int* __restrict__ src,
                                                             const int* __restrict__ dst,
                                                             int* __restrict__ bcursor,
                                                             int* __restrict__ sorted, int E) {
    __shared__ int lhist[NBUK];
    __shared__ int lbase[NBUK];
    for (int i = threadIdx.x; i < NBUK; i += 256) lhist[i] = 0;
    __syncthreads();
    int base_i = blockIdx.x * SCAT_TILE;
    int s[SCAT_EPT], d[SCAT_EPT], lp[SCAT_EPT];
#pragma unroll
    for (int k = 0; k < SCAT_EPT; ++k) {
        int i = base_i + k * 256 + threadIdx.x;
        if (i < E) {
            s[k] = src[i];
            d[k] = dst[i];
            lp[k] = atomicAdd(&lhist[d[k] >> BUK_SHIFT], 1);
        }
    }
    __syncthreads();
    for (int b = threadIdx.x; b < NBUK; b += 256) {
        int c = lhist[b];
        lbase[b] = c ? atomicAdd(&bcursor[b], c) : 0;
    }
    __syncthreads();
#pragma unroll
    for (int k = 0; k < SCAT_EPT; ++k) {
        int i = base_i + k * 256 + threadIdx.x;
        if (i < E) {
            int b = d[k] >> BUK_SHIFT;
            sorted[lbase[b] + lp[k]] = (s[k] << BUK_SHIFT) | (d[k] & 127);
        }
    }
}

// ---- fused: per-bucket count + dinv + rowse(start,end) + gapped CSR fill ----
__global__ __launch_bounds__(256) void bucket_build_kernel(const int* __restrict__ sorted,
                                                           const int* __restrict__ bcursor,
                                                           int2* __restrict__ rowse,
                                                           float* __restrict__ dinv,
                                                           int* __restrict__ esrc, int n) {
    __shared__ int ncnt[128];
    __shared__ int sc[128];
    __shared__ int lbase[128];
    __shared__ int lcur[128];
    int tid = threadIdx.x;
    int b = blockIdx.x;
    int start = b * BUK_CAP;
    int end = bcursor[b];            // final cursor = start + bucket count
    if (tid < 128) ncnt[tid] = 0;
    __syncthreads();
    for (int j = start + tid; j < end; j += 256)
        atomicAdd(&ncnt[sorted[j] & 127], 1);
    __syncthreads();
    if (tid < 128) sc[tid] = ncnt[tid];
    __syncthreads();
    for (int off = 1; off < 128; off <<= 1) {
        int v = 0;
        if (tid < 128 && tid >= off) v = sc[tid - off];
        __syncthreads();
        if (tid < 128) sc[tid] += v;
        __syncthreads();
    }
    if (tid < 128) {
        int excl = sc[tid] - ncnt[tid];
        int pos = start + excl;
        lbase[tid] = pos;
        lcur[tid] = 0;
        int node = (b << BUK_SHIFT) + tid;
        if (node < n) {
            rowse[node] = make_int2(pos, pos + ncnt[tid]);
            dinv[node] = rsqrtf((float)ncnt[tid] + 1.0f);
        }
    }
    __syncthreads();
    for (int j = start + tid; j < end; j += 256) {
        int p = sorted[j];
        int ln = p & 127;
        int off = atomicAdd(&lcur[ln], 1);
        esrc[lbase[ln] + off] = p >> BUK_SHIFT;
    }
}

// ---------------- MFMA GEMM: C[M][NOUT] = A[M][K] @ Wt^T ----------------
// EPI=0: bf16 C = A@W ; EPI=1: bf16 C = dinv*relu(A@W+b) ; EPI=2: fp8 C = fp8(S*(A@W))
template <int K, int NOUT, int EPI, int A_F32>
__global__ __launch_bounds__(256) void mfma_gemm_kernel(const void* __restrict__ Aptr,
                                                        const u16* __restrict__ Wt,
                                                        const float* __restrict__ bias,
                                                        const float* __restrict__ dinv,
                                                        void* __restrict__ C, int M) {
    constexpr int KP = K + 8;
    constexpr int NK = K / 32;
    constexpr int NCT = NOUT / 16;
    constexpr int SUBS = 2;
    __shared__ u16 wlds[NOUT * KP];
    int tid = threadIdx.x;
    constexpr int TOT = NOUT * K / 8;
    const uint4* wt4 = (const uint4*)Wt;
    for (int i = tid; i < TOT; i += 256) {
        int r = i / (K / 8), kc = i % (K / 8);
        *(uint4*)&wlds[r * KP + kc * 8] = wt4[i];
    }
    __syncthreads();

    int lane = tid & 63;
    int w = tid >> 6;
    int row0 = blockIdx.x * 128 + w * 32;

    short8 afr[SUBS][NK];
#pragma unroll
    for (int sub = 0; sub < SUBS; ++sub) {
        int arow = row0 + sub * 16 + (lane & 15);
        arow = min(arow, M - 1);
        if (A_F32) {
            const float* Af = (const float*)Aptr;
            float dv = dinv[arow];
#pragma unroll
            for (int ks = 0; ks < NK; ++ks) {
                int k0 = ks * 32 + (lane >> 4) * 8;
                const float4* p = (const float4*)(Af + (size_t)arow * K + k0);
                float4 uu = p[0], vv = p[1];
                uint4 q;
                q.x = bfpack(dv * uu.x, dv * uu.y);
                q.y = bfpack(dv * uu.z, dv * uu.w);
                q.z = bfpack(dv * vv.x, dv * vv.y);
                q.w = bfpack(dv * vv.z, dv * vv.w);
                afr[sub][ks] = *(short8*)&q;
            }
        } else {
            const u16* Ab = (const u16*)Aptr;
#pragma unroll
            for (int ks = 0; ks < NK; ++ks) {
                int k0 = ks * 32 + (lane >> 4) * 8;
                afr[sub][ks] = *(const short8*)(Ab + (size_t)arow * K + k0);
            }
        }
    }

    for (int ct = 0; ct < NCT; ++ct) {
        int bcol = ct * 16 + (lane & 15);
        short8 bfr[NK];
#pragma unroll
        for (int ks = 0; ks < NK; ++ks) {
            int k0 = ks * 32 + (lane >> 4) * 8;
            bfr[ks] = *(const short8*)&wlds[bcol * KP + k0];
        }
        float bc = 0.0f;
        if (EPI == 1) bc = bias[bcol];
#pragma unroll
        for (int sub = 0; sub < SUBS; ++sub) {
            f32x4 acc = {0.0f, 0.0f, 0.0f, 0.0f};
#pragma unroll
            for (int ks = 0; ks < NK; ++ks)
                acc = __builtin_amdgcn_mfma_f32_16x16x32_bf16(afr[sub][ks], bfr[ks], acc,
                                                              0, 0, 0);
            int rbase = row0 + sub * 16 + (lane >> 4) * 4;
            if (rbase < M) {
                if (EPI == 0) {
#pragma unroll
                    for (int j = 0; j < 4; ++j)
                        ((u16*)C)[(size_t)(rbase + j) * NOUT + bcol] = (u16)bf1(acc[j]);
                } else if (EPI == 1) {
                    float4 dv4 = *(const float4*)(dinv + rbase);
                    float dvv[4] = {dv4.x, dv4.y, dv4.z, dv4.w};
#pragma unroll
                    for (int j = 0; j < 4; ++j) {
                        float o = dvv[j] * fmaxf(acc[j] + bc, 0.0f);
                        ((u16*)C)[(size_t)(rbase + j) * NOUT + bcol] = (u16)bf1(o);
                    }
                } else {   // EPI == 2: fp8 out, pre-scaled by FP8_S
#pragma unroll
                    for (int j = 0; j < 4; ++j)
                        ((u8*)C)[(size_t)(rbase + j) * NOUT + bcol] = fp8_1(acc[j] * FP8_S);
                }
            }
        }
    }
}

// ---- agg1 (fp8 TS1 gather, F=64): h1' = dv * relu(dv*(1/S)*(sum+self) + b1), bf16 out ----
// TPN=8 lanes x uint2 (8 fp8 = 8B/lane), EPG=8 groups, 2x-unroll: same loop shape
// as the proven bf16 agg; bytes halved at constant transaction count.
__global__ __launch_bounds__(256) void pull_agg1_f8_kernel(const uint2* __restrict__ TS,
                                                           const int2* __restrict__ rowse,
                                                           const int* __restrict__ esrc,
                                                           const float* __restrict__ dinv,
                                                           const float* __restrict__ bias,
                                                           uint4* __restrict__ OUT, int n) {
    constexpr int TPN = 8;
    constexpr int EPG = 8;
    int wid = threadIdx.x >> 6;
    int lane = threadIdx.x & 63;
    int node = blockIdx.x * 4 + wid;
    if (node >= n) return;
    int t = lane % TPN;
    int g = lane / TPN;
    float acc[8] = {0, 0, 0, 0, 0, 0, 0, 0};
    float f[8];
    int2 se = rowse[node];
    int j = se.x + g;
    for (; j + EPG < se.y; j += 2 * EPG) {
        int s0 = esrc[j];
        int s1 = esrc[j + EPG];
        uint2 v0 = TS[(size_t)s0 * TPN + t];
        uint2 v1 = TS[(size_t)s1 * TPN + t];
        unpack8f8(v0, f);
#pragma unroll
        for (int k = 0; k < 8; ++k) acc[k] += f[k];
        unpack8f8(v1, f);
#pragma unroll
        for (int k = 0; k < 8; ++k) acc[k] += f[k];
    }
    if (j < se.y) {
        unpack8f8(TS[(size_t)esrc[j] * TPN + t], f);
#pragma unroll
        for (int k = 0; k < 8; ++k) acc[k] += f[k];
    }
#pragma unroll
    for (int k = 0; k < 8; ++k) {
        acc[k] += __shfl_xor(acc[k], 8, 64);
        acc[k] += __shfl_xor(acc[k], 16, 64);
        acc[k] += __shfl_xor(acc[k], 32, 64);
    }
    if (g == 0) {
        unpack8f8(TS[(size_t)node * TPN + t], f);   // self-loop term
        float dv = dinv[node];
        float dvs = dv * FP8_INV_S;
        const float4* bias4 = (const float4*)bias;
        float4 b0 = bias4[t * 2], b1v = bias4[t * 2 + 1];
        float bb[8] = {b0.x, b0.y, b0.z, b0.w, b1v.x, b1v.y, b1v.z, b1v.w};
        float o[8];
#pragma unroll
        for (int k = 0; k < 8; ++k)
            o[k] = dv * fmaxf(dvs * (acc[k] + f[k]) + bb[k], 0.0f);
        uint4 pv;
        pv.x = bfpack(o[0], o[1]); pv.y = bfpack(o[2], o[3]);
        pv.z = bfpack(o[4], o[5]); pv.w = bfpack(o[6], o[7]);
        OUT[(size_t)node * TPN + t] = pv;
    }
}

// ---- edge-parallel wave aggregation (F=64 bf16), 2x-unrolled gather ----
// EPI=2: out = dv * acc   (pre-agg2 on pre-scaled h1', bf16 out)
template <int F, int OUT_BF, int EPI>
__global__ __launch_bounds__(256) void pull_agg_w_kernel(const uint4* __restrict__ TS,
                                                         const int2* __restrict__ rowse,
                                                         const int* __restrict__ esrc,
                                                         const float* __restrict__ dinv,
                                                         const float* __restrict__ bias,
                                                         void* __restrict__ OUT, int n) {
    constexpr int TPN = F / 8;
    constexpr int EPG = 64 / TPN;
    int wid = threadIdx.x >> 6;
    int lane = threadIdx.x & 63;
    int node = blockIdx.x * 4 + wid;
    if (node >= n) return;
    int t = lane % TPN;
    int g = lane / TPN;
    float acc[8] = {0, 0, 0, 0, 0, 0, 0, 0};
    float f[8];
    int2 se = rowse[node];
    int j = se.x + g;
    for (; j + EPG < se.y; j += 2 * EPG) {
        int s0 = esrc[j];
        int s1 = esrc[j + EPG];
        uint4 v0 = TS[(size_t)s0 * TPN + t];
        uint4 v1 = TS[(size_t)s1 * TPN + t];
        unpack8(v0, f);
#pragma unroll
        for (int k = 0; k < 8; ++k) acc[k] += f[k];
        unpack8(v1, f);
#pragma unroll
        for (int k = 0; k < 8; ++k) acc[k] += f[k];
    }
    if (j < se.y) {
        int s = esrc[j];
        unpack8(TS[(size_t)s * TPN + t], f);
#pragma unroll
        for (int k = 0; k < 8; ++k) acc[k] += f[k];
    }
#pragma unroll
    for (int k = 0; k < 8; ++k) {
#pragma unroll
        for (int m = TPN; m < 64; m <<= 1) acc[k] += __shfl_xor(acc[k], m, 64);
    }
    if (g == 0) {
        unpack8(TS[(size_t)node * TPN + t], f);
#pragma unroll
        for (int k = 0; k < 8; ++k) acc[k] += f[k];
        float dv = dinv[node];
        float o[8];
        if (EPI == 2) {
#pragma unroll
            for (int k = 0; k < 8; ++k) o[k] = dv * acc[k];
        } else {
            const float4* bias4 = (const float4*)bias;
            float4 b0 = bias4[t * 2], b1v = bias4[t * 2 + 1];
            float bb[8] = {b0.x, b0.y, b0.z, b0.w, b1v.x, b1v.y, b1v.z, b1v.w};
#pragma unroll
            for (int k = 0; k < 8; ++k) o[k] = fmaxf(dv * acc[k] + bb[k], 0.0f);
            if (EPI == 1) {
#pragma unroll
                for (int k = 0; k < 8; ++k) o[k] *= dv;
            }
        }
        if (OUT_BF) {
            uint4 pv;
            pv.x = bfpack(o[0], o[1]); pv.y = bfpack(o[2], o[3]);
            pv.z = bfpack(o[4], o[5]); pv.w = bfpack(o[6], o[7]);
            ((uint4*)OUT)[(size_t)node * TPN + t] = pv;
        } else {
            float4* O4 = (float4*)OUT;
            O4[(size_t)node * (F / 4) + t * 2] = make_float4(o[0], o[1], o[2], o[3]);
            O4[(size_t)node * (F / 4) + t * 2 + 1] = make_float4(o[4], o[5], o[6], o[7]);
        }
    }
}

// ---- fused layer-3 aggregation + mean-pool, fp8 TS3 gather (round-12 version) ----
// 4 waves/block, ONE node per wave, grid = n/4 EXACT. TPN=16 lanes x uint2
// (8 fp8 each), 4 edge groups x 4-unroll = 16 chains. LDS run-length reduce.
__global__ __launch_bounds__(256) void pull_agg_pool_kernel(const uint2* __restrict__ TS,
                                                            const int2* __restrict__ rowse,
                                                            const int* __restrict__ esrc,
                                                            const float* __restrict__ dinv,
                                                            const float* __restrict__ bias,
                                                            const int* __restrict__ batch,
                                                            float* __restrict__ PS, int n) {
    constexpr int TPN = 16;   // F=128: 16 lanes x 8 feats (8 B fp8 per lane)
    constexpr int EPG = 4;
    __shared__ float hrow[4][128];
    __shared__ int ib[4];
    int wid = threadIdx.x >> 6;
    int lane = threadIdx.x & 63;
    int node = blockIdx.x * 4 + wid;   // always < n (grid exact)
    int t = lane % TPN;
    int g = lane / TPN;
    float acc[8] = {0, 0, 0, 0, 0, 0, 0, 0};
    float f[8];
    int2 se = rowse[node];
    int j = se.x + g;
    int end = se.y;
    for (; j + 3 * EPG < end; j += 4 * EPG) {
        int s0 = esrc[j];
        int s1 = esrc[j + EPG];
        int s2 = esrc[j + 2 * EPG];
        int s3 = esrc[j + 3 * EPG];
        uint2 v0 = TS[(size_t)s0 * TPN + t];
        uint2 v1 = TS[(size_t)s1 * TPN + t];
        uint2 v2 = TS[(size_t)s2 * TPN + t];
        uint2 v3 = TS[(size_t)s3 * TPN + t];
        unpack8f8(v0, f);
#pragma unroll
        for (int k = 0; k < 8; ++k) acc[k] += f[k];
        unpack8f8(v1, f);
#pragma unroll
        for (int k = 0; k < 8; ++k) acc[k] += f[k];
        unpack8f8(v2, f);
#pragma unroll
        for (int k = 0; k < 8; ++k) acc[k] += f[k];
        unpack8f8(v3, f);
#pragma unroll
        for (int k = 0; k < 8; ++k) acc[k] += f[k];
    }
    for (; j + EPG < end; j += 2 * EPG) {
        int s0 = esrc[j];
        int s1 = esrc[j + EPG];
        uint2 v0 = TS[(size_t)s0 * TPN + t];
        uint2 v1 = TS[(size_t)s1 * TPN + t];
        unpack8f8(v0, f);
#pragma unroll
        for (int k = 0; k < 8; ++k) acc[k] += f[k];
        unpack8f8(v1, f);
#pragma unroll
        for (int k = 0; k < 8; ++k) acc[k] += f[k];
    }
    if (j < end) {
        unpack8f8(TS[(size_t)esrc[j] * TPN + t], f);
#pragma unroll
        for (int k = 0; k < 8; ++k) acc[k] += f[k];
    }
#pragma unroll
    for (int k = 0; k < 8; ++k) {
        acc[k] += __shfl_xor(acc[k], 16, 64);
        acc[k] += __shfl_xor(acc[k], 32, 64);
    }
    if (g == 0) {
        unpack8f8(TS[(size_t)node * TPN + t], f);
        float dvs = dinv[node] * FP8_INV_S;   // undo fp8 pre-scale
        const float4* bias4 = (const float4*)bias;
        float4 b0 = bias4[t * 2], b1v = bias4[t * 2 + 1];
        float bb[8] = {b0.x, b0.y, b0.z, b0.w, b1v.x, b1v.y, b1v.z, b1v.w};
#pragma unroll
        for (int k = 0; k < 8; ++k)
            hrow[wid][t * 8 + k] = fmaxf(dvs * (acc[k] + f[k]) + bb[k], 0.0f);
        if (lane == 0) ib[wid] = batch[node];
    }
    __syncthreads();
    // run-length reduce 4 node rows by graph id (batch sorted)
    int tf = threadIdx.x;
    if (tf < 128) {
        float run = hrow[0][tf];
        int cg = ib[0];
        for (int w = 1; w < 4; ++w) {
            int gg = ib[w];
            if (gg != cg) {
                atomicAdd(&PS[(size_t)cg * 128 + tf], run);
                run = hrow[w][tf];
                cg = gg;
            } else {
                run += hrow[w][tf];
            }
        }
        atomicAdd(&PS[(size_t)cg * 128 + tf], run);
    }
}

// ---------------- FC from pooled sums: out = (PS[g]/cnt) @ Wfc + bfc ----------------
__global__ __launch_bounds__(128) void fc_kernel(const float* __restrict__ PS,
                                                 const int* __restrict__ batch,
                                                 const float* __restrict__ Wfc,
                                                 const float* __restrict__ bfc,
                                                 float* __restrict__ OUT, int n) {
    int g = blockIdx.x;
    __shared__ int se[2];
    __shared__ float pooled[128];
    if (threadIdx.x < 2) {
        int target = g + threadIdx.x;
        int lo = 0, hi = n;
        while (lo < hi) {
            int mid = (lo + hi) >> 1;
            if (batch[mid] < target) lo = mid + 1; else hi = mid;
        }
        se[threadIdx.x] = lo;
    }
    __syncthreads();
    float cntf = (float)max(se[1] - se[0], 1);
    pooled[threadIdx.x] = PS[(size_t)g * 128 + threadIdx.x] / cntf;
    __syncthreads();
    if (threadIdx.x < 10) {
        float o = bfc[threadIdx.x];
        for (int k = 0; k < 128; ++k) o += pooled[k] * Wfc[k * 10 + threadIdx.x];
        OUT[g * 10 + threadIdx.x] = o;
    }
}

extern "C" void kernel_launch(void* const* d_in, const int* in_sizes, int n_in,
                              void* d_out, int out_size, void* d_ws, size_t ws_size,
                              hipStream_t stream) {
    const int N = N_NODES, E = N_EDGES, G = N_GRAPHS;
    const float* x = (const float*)d_in[0];
    const int* ei = (const int*)d_in[1];
    const int* batch = (const int*)d_in[2];
    const float* W1 = (const float*)d_in[3];
    const float* b1 = (const float*)d_in[4];
    const float* W2 = (const float*)d_in[5];
    const float* b2 = (const float*)d_in[6];
    const float* W3 = (const float*)d_in[7];
    const float* b3 = (const float*)d_in[8];
    const float* Wfc = (const float*)d_in[9];
    const float* bfc = (const float*)d_in[10];
    const int* src = ei;
    const int* dst = ei + E;

    char* ws = (char*)d_ws;
    size_t off = 0;
    auto alloc = [&](size_t bytes) {
        void* p = ws + off;
        off = (off + bytes + 255) & ~(size_t)255;
        return p;
    };
    float* dinv = (float*)alloc((size_t)N * 4);
    int2* rowse = (int2*)alloc((size_t)N * 8);
    int* bcursor = (int*)alloc((size_t)NBUK * 4);
    int* esrc = (int*)alloc((size_t)NBUK * BUK_CAP * 4);   // gapped, ~8 MB
    u16* W1t = (u16*)alloc((size_t)64 * 128 * 2);
    u16* W2t = (u16*)alloc((size_t)128 * 64 * 2);
    u16* W3t = (u16*)alloc((size_t)128 * 128 * 2);
    u8* TS1 = (u8*)alloc((size_t)N * 64);            // fp8 [N][64], scaled by FP8_S
    u16* H1S = (u16*)alloc((size_t)N * 64 * 2);      // bf16 [N][64], pre-scaled
    u16* G2 = (u16*)alloc((size_t)N * 64 * 2);       // bf16 [N][64]
    u16* H2S = (u16*)alloc((size_t)N * 128 * 2);     // bf16 [N][128], pre-scaled
    u8* TS3 = (u8*)alloc((size_t)N * 128);           // fp8 [N][128], scaled by FP8_S
    float* PS = (float*)alloc((size_t)G * 128 * 4);  // pooled sums
    int* sorted = (int*)TS3;  // gapped packed edges (8 MB) alias TS3 (12.8 MB)

    // ---- setup: W conversion + PS zero + cursor init (one kernel, no memsets) ----
    setup_kernel<<<164, 256, 0, stream>>>(W1, W2, W3, W1t, W2t, W3t, PS, bcursor);
    // ---- graph preprocessing: gapped bucket sort + CSR build ----
    const int NTILES = (E + SCAT_TILE - 1) / SCAT_TILE;
    bucket_scatter_kernel<<<NTILES, 256, 0, stream>>>(src, dst, bcursor, sorted, E);
    bucket_build_kernel<<<NBUK, 256, 0, stream>>>(sorted, bcursor, rowse, dinv, esrc, N);

    const int GEMM_GRID = (N + 127) / 128;   // 782
    const int AGG_GRID = N / 4;              // 25000 (N%4==0)
    // ---- layer 1: 128 -> 64 : fp8 ts1 = fp8(S*(dinv*x)@W1); agg1 -> bf16 h1' ----
    mfma_gemm_kernel<128, 64, 2, 1><<<GEMM_GRID, 256, 0, stream>>>(x, W1t, nullptr, dinv,
                                                                   TS1, N);
    pull_agg1_f8_kernel<<<AGG_GRID, 256, 0, stream>>>((const uint2*)TS1, rowse, esrc,
                                                      dinv, b1, (uint4*)H1S, N);
    // ---- layer 2: 64 -> 128 (bf16 path) ----
    pull_agg_w_kernel<64, 1, 2><<<AGG_GRID, 256, 0, stream>>>((const uint4*)H1S, rowse,
                                                              esrc, dinv, nullptr, G2, N);
    mfma_gemm_kernel<64, 128, 1, 0><<<GEMM_GRID, 256, 0, stream>>>(G2, W2t, b2, dinv,
                                                                   H2S, N);
    // ---- layer 3: 128 -> 128, fp8 ts3; aggregation fused with mean-pool ----
    mfma_gemm_kernel<128, 128, 2, 0><<<GEMM_GRID, 256, 0, stream>>>(H2S, W3t, nullptr, dinv,
                                                                    TS3, N);
    pull_agg_pool_kernel<<<AGG_GRID, 256, 0, stream>>>((const uint2*)TS3, rowse, esrc,
                                                       dinv, b3, batch, PS, N);
    // ---- FC from pooled sums ----
    fc_kernel<<<G, 128, 0, stream>>>(PS, batch, Wfc, bfc, (float*)d_out, N);
}

// Round 16
// 232.811 us; speedup vs baseline: 1.0533x; 1.0025x over previous
//
#include <hip/hip_runtime.h>
#include <hip/hip_bf16.h>

typedef unsigned int u32;
typedef unsigned short u16;
typedef unsigned char u8;
typedef __attribute__((ext_vector_type(8))) short short8;
typedef __attribute__((ext_vector_type(4))) float f32x4;
typedef __attribute__((ext_vector_type(2))) float f32x2;

#define N_NODES 100000
#define N_EDGES 1600000
#define N_GRAPHS 1024
#define BUK_SHIFT 7         // 128 nodes per bucket
#define NBUK 782            // ceil(100000 / 128)
#define BUK_CAP 2560        // mean fill 2046, sd ~45 -> +11 sigma headroom
#define SCAT_EPT 16         // edges per thread in bucket_scatter
#define SCAT_TILE (256 * SCAT_EPT)
#define FP8_S 64.0f         // pre-scale into e4m3 normal range
#define FP8_INV_S (1.0f / 64.0f)

// ---- bf16 helpers (RNE) ----
__device__ __forceinline__ float bflo(u32 u) { return __uint_as_float(u << 16); }
__device__ __forceinline__ float bfhi(u32 u) { return __uint_as_float(u & 0xFFFF0000u); }
__device__ __forceinline__ u32 bf1(float a) {
    u32 ua = __float_as_uint(a);
    ua += 0x7FFF + ((ua >> 16) & 1);
    return ua >> 16;
}
__device__ __forceinline__ u32 bfpack(float a, float b) {
    u32 ua = __float_as_uint(a);
    u32 ub = __float_as_uint(b);
    ua += 0x7FFF + ((ua >> 16) & 1);
    ub += 0x7FFF + ((ub >> 16) & 1);
    return (ua >> 16) | (ub & 0xFFFF0000u);
}
__device__ __forceinline__ void unpack8(uint4 v, float* f) {
    f[0] = bflo(v.x); f[1] = bfhi(v.x); f[2] = bflo(v.y); f[3] = bfhi(v.y);
    f[4] = bflo(v.z); f[5] = bfhi(v.z); f[6] = bflo(v.w); f[7] = bfhi(v.w);
}
// ---- fp8 (e4m3) helpers: HW cvt, 8 values per uint2 ----
__device__ __forceinline__ void unpack8f8(uint2 v, float* f) {
    f32x2 p0 = __builtin_amdgcn_cvt_pk_f32_fp8((int)v.x, false);
    f32x2 p1 = __builtin_amdgcn_cvt_pk_f32_fp8((int)v.x, true);
    f32x2 p2 = __builtin_amdgcn_cvt_pk_f32_fp8((int)v.y, false);
    f32x2 p3 = __builtin_amdgcn_cvt_pk_f32_fp8((int)v.y, true);
    f[0] = p0.x; f[1] = p0.y; f[2] = p1.x; f[3] = p1.y;
    f[4] = p2.x; f[5] = p2.y; f[6] = p3.x; f[7] = p3.y;
}
__device__ __forceinline__ u8 fp8_1(float a) {
    int r = __builtin_amdgcn_cvt_pk_fp8_f32(a, a, 0, false);
    return (u8)(r & 0xFF);
}
__device__ __forceinline__ u32 fp8x4(float a, float b, float c, float d) {
    int lo = __builtin_amdgcn_cvt_pk_fp8_f32(a, b, 0, false);     // [15:0]
    int w = __builtin_amdgcn_cvt_pk_fp8_f32(c, d, lo, true);      // [31:16]
    return (u32)w;
}

// ---- setup kernel: W transposes->bf16, zero PS, init gapped bucket cursors ----
__global__ __launch_bounds__(256) void setup_kernel(const float* __restrict__ W1,
                                                    const float* __restrict__ W2,
                                                    const float* __restrict__ W3,
                                                    u16* __restrict__ W1t,
                                                    u16* __restrict__ W2t,
                                                    u16* __restrict__ W3t,
                                                    float* __restrict__ PS,
                                                    int* __restrict__ bcursor) {
    int i = blockIdx.x * 256 + threadIdx.x;
    if (i < 8192) {                 // W1: [128][64] -> W1t [64][128]
        int n = i / 128, k = i % 128;
        W1t[i] = (u16)bf1(W1[(size_t)k * 64 + n]);
    } else if (i < 16384) {         // W2: [64][128] -> W2t [128][64]
        int j = i - 8192;
        int n = j / 64, k = j % 64;
        W2t[j] = (u16)bf1(W2[(size_t)k * 128 + n]);
    } else if (i < 32768) {         // W3: [128][128] -> W3t [128][128]
        int j = i - 16384;
        int n = j / 128, k = j % 128;
        W3t[j] = (u16)bf1(W3[(size_t)k * 128 + n]);
    } else if (i < 40960) {         // zero PS
        int j = i - 32768;
        float4 z = make_float4(0.f, 0.f, 0.f, 0.f);
        float4* p = (float4*)(PS + (size_t)j * 16);
        p[0] = z; p[1] = z; p[2] = z; p[3] = z;
    } else if (i < 40960 + NBUK) {  // gapped bucket cursors
        int b = i - 40960;
        bcursor[b] = b * BUK_CAP;
    }
}

// ---------------- scatter edges into gapped bucket order (packed) ----------------
__global__ __launch_bounds__(256) void bucket_scatter_kernel(const int* __restrict__ src,
                                                             const int* __restrict__ dst,
                                                             int* __restrict__ bcursor,
                                                             int* __restrict__ sorted, int E) {
    __shared__ int lhist[NBUK];
    __shared__ int lbase[NBUK];
    for (int i = threadIdx.x; i < NBUK; i += 256) lhist[i] = 0;
    __syncthreads();
    int base_i = blockIdx.x * SCAT_TILE;
    int s[SCAT_EPT], d[SCAT_EPT], lp[SCAT_EPT];
#pragma unroll
    for (int k = 0; k < SCAT_EPT; ++k) {
        int i = base_i + k * 256 + threadIdx.x;
        if (i < E) {
            s[k] = src[i];
            d[k] = dst[i];
            lp[k] = atomicAdd(&lhist[d[k] >> BUK_SHIFT], 1);
        }
    }
    __syncthreads();
    for (int b = threadIdx.x; b < NBUK; b += 256) {
        int c = lhist[b];
        lbase[b] = c ? atomicAdd(&bcursor[b], c) : 0;
    }
    __syncthreads();
#pragma unroll
    for (int k = 0; k < SCAT_EPT; ++k) {
        int i = base_i + k * 256 + threadIdx.x;
        if (i < E) {
            int b = d[k] >> BUK_SHIFT;
            sorted[lbase[b] + lp[k]] = (s[k] << BUK_SHIFT) | (d[k] & 127);
        }
    }
}

// ---- fused: per-bucket count + dinv + rowse(start,end) + gapped CSR fill ----
__global__ __launch_bounds__(256) void bucket_build_kernel(const int* __restrict__ sorted,
                                                           const int* __restrict__ bcursor,
                                                           int2* __restrict__ rowse,
                                                           float* __restrict__ dinv,
                                                           int* __restrict__ esrc, int n) {
    __shared__ int ncnt[128];
    __shared__ int sc[128];
    __shared__ int lbase[128];
    __shared__ int lcur[128];
    int tid = threadIdx.x;
    int b = blockIdx.x;
    int start = b * BUK_CAP;
    int end = bcursor[b];            // final cursor = start + bucket count
    if (tid < 128) ncnt[tid] = 0;
    __syncthreads();
    for (int j = start + tid; j < end; j += 256)
        atomicAdd(&ncnt[sorted[j] & 127], 1);
    __syncthreads();
    if (tid < 128) sc[tid] = ncnt[tid];
    __syncthreads();
    for (int off = 1; off < 128; off <<= 1) {
        int v = 0;
        if (tid < 128 && tid >= off) v = sc[tid - off];
        __syncthreads();
        if (tid < 128) sc[tid] += v;
        __syncthreads();
    }
    if (tid < 128) {
        int excl = sc[tid] - ncnt[tid];
        int pos = start + excl;
        lbase[tid] = pos;
        lcur[tid] = 0;
        int node = (b << BUK_SHIFT) + tid;
        if (node < n) {
            rowse[node] = make_int2(pos, pos + ncnt[tid]);
            dinv[node] = rsqrtf((float)ncnt[tid] + 1.0f);
        }
    }
    __syncthreads();
    for (int j = start + tid; j < end; j += 256) {
        int p = sorted[j];
        int ln = p & 127;
        int off = atomicAdd(&lcur[ln], 1);
        esrc[lbase[ln] + off] = p >> BUK_SHIFT;
    }
}

// ---------------- MFMA GEMM: C[M][NOUT] = A[M][K] @ Wt^T ----------------
// EPI=0: bf16 C = A@W ; EPI=1: bf16 C = dinv*relu(A@W+b) ; EPI=2: fp8 C = fp8(S*(A@W))
template <int K, int NOUT, int EPI, int A_F32>
__global__ __launch_bounds__(256) void mfma_gemm_kernel(const void* __restrict__ Aptr,
                                                        const u16* __restrict__ Wt,
                                                        const float* __restrict__ bias,
                                                        const float* __restrict__ dinv,
                                                        void* __restrict__ C, int M) {
    constexpr int KP = K + 8;
    constexpr int NK = K / 32;
    constexpr int NCT = NOUT / 16;
    constexpr int SUBS = 2;
    __shared__ u16 wlds[NOUT * KP];
    int tid = threadIdx.x;
    constexpr int TOT = NOUT * K / 8;
    const uint4* wt4 = (const uint4*)Wt;
    for (int i = tid; i < TOT; i += 256) {
        int r = i / (K / 8), kc = i % (K / 8);
        *(uint4*)&wlds[r * KP + kc * 8] = wt4[i];
    }
    __syncthreads();

    int lane = tid & 63;
    int w = tid >> 6;
    int row0 = blockIdx.x * 128 + w * 32;

    short8 afr[SUBS][NK];
#pragma unroll
    for (int sub = 0; sub < SUBS; ++sub) {
        int arow = row0 + sub * 16 + (lane & 15);
        arow = min(arow, M - 1);
        if (A_F32) {
            const float* Af = (const float*)Aptr;
            float dv = dinv[arow];
#pragma unroll
            for (int ks = 0; ks < NK; ++ks) {
                int k0 = ks * 32 + (lane >> 4) * 8;
                const float4* p = (const float4*)(Af + (size_t)arow * K + k0);
                float4 uu = p[0], vv = p[1];
                uint4 q;
                q.x = bfpack(dv * uu.x, dv * uu.y);
                q.y = bfpack(dv * uu.z, dv * uu.w);
                q.z = bfpack(dv * vv.x, dv * vv.y);
                q.w = bfpack(dv * vv.z, dv * vv.w);
                afr[sub][ks] = *(short8*)&q;
            }
        } else {
            const u16* Ab = (const u16*)Aptr;
#pragma unroll
            for (int ks = 0; ks < NK; ++ks) {
                int k0 = ks * 32 + (lane >> 4) * 8;
                afr[sub][ks] = *(const short8*)(Ab + (size_t)arow * K + k0);
            }
        }
    }

    for (int ct = 0; ct < NCT; ++ct) {
        int bcol = ct * 16 + (lane & 15);
        short8 bfr[NK];
#pragma unroll
        for (int ks = 0; ks < NK; ++ks) {
            int k0 = ks * 32 + (lane >> 4) * 8;
            bfr[ks] = *(const short8*)&wlds[bcol * KP + k0];
        }
        float bc = 0.0f;
        if (EPI == 1) bc = bias[bcol];
#pragma unroll
        for (int sub = 0; sub < SUBS; ++sub) {
            f32x4 acc = {0.0f, 0.0f, 0.0f, 0.0f};
#pragma unroll
            for (int ks = 0; ks < NK; ++ks)
                acc = __builtin_amdgcn_mfma_f32_16x16x32_bf16(afr[sub][ks], bfr[ks], acc,
                                                              0, 0, 0);
            int rbase = row0 + sub * 16 + (lane >> 4) * 4;
            if (rbase < M) {
                if (EPI == 0) {
#pragma unroll
                    for (int j = 0; j < 4; ++j)
                        ((u16*)C)[(size_t)(rbase + j) * NOUT + bcol] = (u16)bf1(acc[j]);
                } else if (EPI == 1) {
                    float4 dv4 = *(const float4*)(dinv + rbase);
                    float dvv[4] = {dv4.x, dv4.y, dv4.z, dv4.w};
#pragma unroll
                    for (int j = 0; j < 4; ++j) {
                        float o = dvv[j] * fmaxf(acc[j] + bc, 0.0f);
                        ((u16*)C)[(size_t)(rbase + j) * NOUT + bcol] = (u16)bf1(o);
                    }
                } else {   // EPI == 2: fp8 out, pre-scaled by FP8_S
#pragma unroll
                    for (int j = 0; j < 4; ++j)
                        ((u8*)C)[(size_t)(rbase + j) * NOUT + bcol] = fp8_1(acc[j] * FP8_S);
                }
            }
        }
    }
}

// ---- F=64 fp8-gather aggregation (TPN=8 lanes x uint2, EPG=8, 2x-unroll) ----
// EPI=1 (agg1): o = dv*relu(dv*(1/S)*(acc+self) + b); write fp8(S*o)  [H1S]
// EPI=2 (agg2): o = dv*(1/S)*(acc+self);              write bf16 o    [G2]
template <int EPI>
__global__ __launch_bounds__(256) void pull_agg_f8_64_kernel(const uint2* __restrict__ TS,
                                                             const int2* __restrict__ rowse,
                                                             const int* __restrict__ esrc,
                                                             const float* __restrict__ dinv,
                                                             const float* __restrict__ bias,
                                                             void* __restrict__ OUT, int n) {
    constexpr int TPN = 8;
    constexpr int EPG = 8;
    int wid = threadIdx.x >> 6;
    int lane = threadIdx.x & 63;
    int node = blockIdx.x * 4 + wid;
    if (node >= n) return;
    int t = lane % TPN;
    int g = lane / TPN;
    float acc[8] = {0, 0, 0, 0, 0, 0, 0, 0};
    float f[8];
    int2 se = rowse[node];
    int j = se.x + g;
    for (; j + EPG < se.y; j += 2 * EPG) {
        int s0 = esrc[j];
        int s1 = esrc[j + EPG];
        uint2 v0 = TS[(size_t)s0 * TPN + t];
        uint2 v1 = TS[(size_t)s1 * TPN + t];
        unpack8f8(v0, f);
#pragma unroll
        for (int k = 0; k < 8; ++k) acc[k] += f[k];
        unpack8f8(v1, f);
#pragma unroll
        for (int k = 0; k < 8; ++k) acc[k] += f[k];
    }
    if (j < se.y) {
        unpack8f8(TS[(size_t)esrc[j] * TPN + t], f);
#pragma unroll
        for (int k = 0; k < 8; ++k) acc[k] += f[k];
    }
#pragma unroll
    for (int k = 0; k < 8; ++k) {
        acc[k] += __shfl_xor(acc[k], 8, 64);
        acc[k] += __shfl_xor(acc[k], 16, 64);
        acc[k] += __shfl_xor(acc[k], 32, 64);
    }
    if (g == 0) {
        unpack8f8(TS[(size_t)node * TPN + t], f);   // self-loop term
        float dv = dinv[node];
        float dvs = dv * FP8_INV_S;
        if (EPI == 1) {
            const float4* bias4 = (const float4*)bias;
            float4 b0 = bias4[t * 2], b1v = bias4[t * 2 + 1];
            float bb[8] = {b0.x, b0.y, b0.z, b0.w, b1v.x, b1v.y, b1v.z, b1v.w};
            float o[8];
#pragma unroll
            for (int k = 0; k < 8; ++k)
                o[k] = dv * fmaxf(dvs * (acc[k] + f[k]) + bb[k], 0.0f) * FP8_S;
            uint2 pv;
            pv.x = fp8x4(o[0], o[1], o[2], o[3]);
            pv.y = fp8x4(o[4], o[5], o[6], o[7]);
            ((uint2*)OUT)[(size_t)node * TPN + t] = pv;
        } else {
            float o[8];
#pragma unroll
            for (int k = 0; k < 8; ++k) o[k] = dvs * (acc[k] + f[k]);
            uint4 pv;
            pv.x = bfpack(o[0], o[1]); pv.y = bfpack(o[2], o[3]);
            pv.z = bfpack(o[4], o[5]); pv.w = bfpack(o[6], o[7]);
            ((uint4*)OUT)[(size_t)node * TPN + t] = pv;
        }
    }
}

// ---- fused layer-3 aggregation + mean-pool, fp8 TS3 gather (round-12 version) ----
// 4 waves/block, ONE node per wave, grid = n/4 EXACT. TPN=16 lanes x uint2
// (8 fp8 each), 4 edge groups x 4-unroll = 16 chains. LDS run-length reduce.
__global__ __launch_bounds__(256) void pull_agg_pool_kernel(const uint2* __restrict__ TS,
                                                            const int2* __restrict__ rowse,
                                                            const int* __restrict__ esrc,
                                                            const float* __restrict__ dinv,
                                                            const float* __restrict__ bias,
                                                            const int* __restrict__ batch,
                                                            float* __restrict__ PS, int n) {
    constexpr int TPN = 16;   // F=128: 16 lanes x 8 feats (8 B fp8 per lane)
    constexpr int EPG = 4;
    __shared__ float hrow[4][128];
    __shared__ int ib[4];
    int wid = threadIdx.x >> 6;
    int lane = threadIdx.x & 63;
    int node = blockIdx.x * 4 + wid;   // always < n (grid exact)
    int t = lane % TPN;
    int g = lane / TPN;
    float acc[8] = {0, 0, 0, 0, 0, 0, 0, 0};
    float f[8];
    int2 se = rowse[node];
    int j = se.x + g;
    int end = se.y;
    for (; j + 3 * EPG < end; j += 4 * EPG) {
        int s0 = esrc[j];
        int s1 = esrc[j + EPG];
        int s2 = esrc[j + 2 * EPG];
        int s3 = esrc[j + 3 * EPG];
        uint2 v0 = TS[(size_t)s0 * TPN + t];
        uint2 v1 = TS[(size_t)s1 * TPN + t];
        uint2 v2 = TS[(size_t)s2 * TPN + t];
        uint2 v3 = TS[(size_t)s3 * TPN + t];
        unpack8f8(v0, f);
#pragma unroll
        for (int k = 0; k < 8; ++k) acc[k] += f[k];
        unpack8f8(v1, f);
#pragma unroll
        for (int k = 0; k < 8; ++k) acc[k] += f[k];
        unpack8f8(v2, f);
#pragma unroll
        for (int k = 0; k < 8; ++k) acc[k] += f[k];
        unpack8f8(v3, f);
#pragma unroll
        for (int k = 0; k < 8; ++k) acc[k] += f[k];
    }
    for (; j + EPG < end; j += 2 * EPG) {
        int s0 = esrc[j];
        int s1 = esrc[j + EPG];
        uint2 v0 = TS[(size_t)s0 * TPN + t];
        uint2 v1 = TS[(size_t)s1 * TPN + t];
        unpack8f8(v0, f);
#pragma unroll
        for (int k = 0; k < 8; ++k) acc[k] += f[k];
        unpack8f8(v1, f);
#pragma unroll
        for (int k = 0; k < 8; ++k) acc[k] += f[k];
    }
    if (j < end) {
        unpack8f8(TS[(size_t)esrc[j] * TPN + t], f);
#pragma unroll
        for (int k = 0; k < 8; ++k) acc[k] += f[k];
    }
#pragma unroll
    for (int k = 0; k < 8; ++k) {
        acc[k] += __shfl_xor(acc[k], 16, 64);
        acc[k] += __shfl_xor(acc[k], 32, 64);
    }
    if (g == 0) {
        unpack8f8(TS[(size_t)node * TPN + t], f);
        float dvs = dinv[node] * FP8_INV_S;   // undo fp8 pre-scale
        const float4* bias4 = (const float4*)bias;
        float4 b0 = bias4[t * 2], b1v = bias4[t * 2 + 1];
        float bb[8] = {b0.x, b0.y, b0.z, b0.w, b1v.x, b1v.y, b1v.z, b1v.w};
#pragma unroll
        for (int k = 0; k < 8; ++k)
            hrow[wid][t * 8 + k] = fmaxf(dvs * (acc[k] + f[k]) + bb[k], 0.0f);
        if (lane == 0) ib[wid] = batch[node];
    }
    __syncthreads();
    // run-length reduce 4 node rows by graph id (batch sorted)
    int tf = threadIdx.x;
    if (tf < 128) {
        float run = hrow[0][tf];
        int cg = ib[0];
        for (int w = 1; w < 4; ++w) {
            int gg = ib[w];
            if (gg != cg) {
                atomicAdd(&PS[(size_t)cg * 128 + tf], run);
                run = hrow[w][tf];
                cg = gg;
            } else {
                run += hrow[w][tf];
            }
        }
        atomicAdd(&PS[(size_t)cg * 128 + tf], run);
    }
}

// ---------------- FC from pooled sums: out = (PS[g]/cnt) @ Wfc + bfc ----------------
__global__ __launch_bounds__(128) void fc_kernel(const float* __restrict__ PS,
                                                 const int* __restrict__ batch,
                                                 const float* __restrict__ Wfc,
                                                 const float* __restrict__ bfc,
                                                 float* __restrict__ OUT, int n) {
    int g = blockIdx.x;
    __shared__ int se[2];
    __shared__ float pooled[128];
    if (threadIdx.x < 2) {
        int target = g + threadIdx.x;
        int lo = 0, hi = n;
        while (lo < hi) {
            int mid = (lo + hi) >> 1;
            if (batch[mid] < target) lo = mid + 1; else hi = mid;
        }
        se[threadIdx.x] = lo;
    }
    __syncthreads();
    float cntf = (float)max(se[1] - se[0], 1);
    pooled[threadIdx.x] = PS[(size_t)g * 128 + threadIdx.x] / cntf;
    __syncthreads();
    if (threadIdx.x < 10) {
        float o = bfc[threadIdx.x];
        for (int k = 0; k < 128; ++k) o += pooled[k] * Wfc[k * 10 + threadIdx.x];
        OUT[g * 10 + threadIdx.x] = o;
    }
}

extern "C" void kernel_launch(void* const* d_in, const int* in_sizes, int n_in,
                              void* d_out, int out_size, void* d_ws, size_t ws_size,
                              hipStream_t stream) {
    const int N = N_NODES, E = N_EDGES, G = N_GRAPHS;
    const float* x = (const float*)d_in[0];
    const int* ei = (const int*)d_in[1];
    const int* batch = (const int*)d_in[2];
    const float* W1 = (const float*)d_in[3];
    const float* b1 = (const float*)d_in[4];
    const float* W2 = (const float*)d_in[5];
    const float* b2 = (const float*)d_in[6];
    const float* W3 = (const float*)d_in[7];
    const float* b3 = (const float*)d_in[8];
    const float* Wfc = (const float*)d_in[9];
    const float* bfc = (const float*)d_in[10];
    const int* src = ei;
    const int* dst = ei + E;

    char* ws = (char*)d_ws;
    size_t off = 0;
    auto alloc = [&](size_t bytes) {
        void* p = ws + off;
        off = (off + bytes + 255) & ~(size_t)255;
        return p;
    };
    float* dinv = (float*)alloc((size_t)N * 4);
    int2* rowse = (int2*)alloc((size_t)N * 8);
    int* bcursor = (int*)alloc((size_t)NBUK * 4);
    int* esrc = (int*)alloc((size_t)NBUK * BUK_CAP * 4);   // gapped, ~8 MB
    u16* W1t = (u16*)alloc((size_t)64 * 128 * 2);
    u16* W2t = (u16*)alloc((size_t)128 * 64 * 2);
    u16* W3t = (u16*)alloc((size_t)128 * 128 * 2);
    u8* TS1 = (u8*)alloc((size_t)N * 64);            // fp8 [N][64], scaled by FP8_S
    u8* H1S = (u8*)alloc((size_t)N * 64);            // fp8 [N][64], scaled by FP8_S
    u16* G2 = (u16*)alloc((size_t)N * 64 * 2);       // bf16 [N][64]
    u16* H2S = (u16*)alloc((size_t)N * 128 * 2);     // bf16 [N][128], pre-scaled
    u8* TS3 = (u8*)alloc((size_t)N * 128);           // fp8 [N][128], scaled by FP8_S
    float* PS = (float*)alloc((size_t)G * 128 * 4);  // pooled sums
    int* sorted = (int*)TS3;  // gapped packed edges (8 MB) alias TS3 (12.8 MB)

    // ---- setup: W conversion + PS zero + cursor init (one kernel, no memsets) ----
    setup_kernel<<<164, 256, 0, stream>>>(W1, W2, W3, W1t, W2t, W3t, PS, bcursor);
    // ---- graph preprocessing: gapped bucket sort + CSR build ----
    const int NTILES = (E + SCAT_TILE - 1) / SCAT_TILE;
    bucket_scatter_kernel<<<NTILES, 256, 0, stream>>>(src, dst, bcursor, sorted, E);
    bucket_build_kernel<<<NBUK, 256, 0, stream>>>(sorted, bcursor, rowse, dinv, esrc, N);

    const int GEMM_GRID = (N + 127) / 128;   // 782
    const int AGG_GRID = N / 4;              // 25000 (N%4==0)
    // ---- layer 1: 128 -> 64 : fp8 ts1; agg1 -> fp8 h1' ----
    mfma_gemm_kernel<128, 64, 2, 1><<<GEMM_GRID, 256, 0, stream>>>(x, W1t, nullptr, dinv,
                                                                   TS1, N);
    pull_agg_f8_64_kernel<1><<<AGG_GRID, 256, 0, stream>>>((const uint2*)TS1, rowse, esrc,
                                                           dinv, b1, H1S, N);
    // ---- layer 2: 64 -> 128 : fp8-gather agg2 -> bf16 g2; gemm2 -> bf16 h2s ----
    pull_agg_f8_64_kernel<2><<<AGG_GRID, 256, 0, stream>>>((const uint2*)H1S, rowse, esrc,
                                                           dinv, nullptr, G2, N);
    mfma_gemm_kernel<64, 128, 1, 0><<<GEMM_GRID, 256, 0, stream>>>(G2, W2t, b2, dinv,
                                                                   H2S, N);
    // ---- layer 3: 128 -> 128, fp8 ts3; aggregation fused with mean-pool ----
    mfma_gemm_kernel<128, 128, 2, 0><<<GEMM_GRID, 256, 0, stream>>>(H2S, W3t, nullptr, dinv,
                                                                    TS3, N);
    pull_agg_pool_kernel<<<AGG_GRID, 256, 0, stream>>>((const uint2*)TS3, rowse, esrc,
                                                       dinv, b3, batch, PS, N);
    // ---- FC from pooled sums ----
    fc_kernel<<<G, 128, 0, stream>>>(PS, batch, Wfc, bfc, (float*)d_out, N);
}